// Round 3
// baseline (962.485 us; speedup 1.0000x reference)
//
#include <hip/hip_runtime.h>
#include <hip/hip_fp16.h>
#include <stdint.h>

// Shapes (fixed by the reference):
//   tract a: x (8192, 4096), W/M (1024, 4096), 64 conns/row
//   tract b: x (8192, 4096), W/M ( 512, 4096), 64 conns/row
//   tract c: x (8192, 2048), W/M ( 512, 2048), 32 conns/row
//   out (8192, 2048) = concat(a:1024, b:512, c:512)

#define BS_TOTAL 8192
#define SRC_A 4096
#define SRC_B 4096
#define SRC_C 2048
#define DST_A 1024
#define DST_B 512
#define DST_C 512
#define K_A 64
#define K_B 64
#define K_C 32
#define OUT_DIM 2048
// LDS word-index spaces of the gather kernels:
//   tract_a_kernel : idx 0..4095  (x_a)
//   tract_bc_kernel: idx 0..4095  (x_b), 4096..6143 (x_c)
#define LDS_OFF_C 4096

// Packed pair: (lds_idx << 16) | fp16_bits(w). idx <= 6143 fits easily.

// ---------------------------------------------------------------------------
// Kernel 1 (compress-v3): one block per unit of 64 consecutive dst rows
// (= the 64 lanes of one wave in the gather kernels). Phase 1: extract each
// row's (idx, w) connections into LDS. Phase 2 (wave 0, lane = row): greedy
// per-step bank matching — at each k-step every lane claims one of its
// unused connections whose bank (idx & 31) has < 2 uses this step (2-way
// LDS access is free on gfx950). Claim via LDS atomic reserve/rollback,
// bounded retries, force-commit fallback. Any permutation of a row's
// connections is numerically correct, so scheduling bugs can only cost
// speed, never correctness.
// ---------------------------------------------------------------------------
__global__ __launch_bounds__(256) void compress_kernel(
    const float* __restrict__ w_a, const float* __restrict__ m_a,
    const float* __restrict__ w_b, const float* __restrict__ m_b,
    const float* __restrict__ w_c, const float* __restrict__ m_c,
    unsigned* __restrict__ pa, unsigned* __restrict__ pb,
    unsigned* __restrict__ pc) {
    __shared__ unsigned s_conn[64][64];  // [row][slot] packed pairs, 16 KB
    __shared__ int s_cnt[64];
    __shared__ int s_bank[32];

    const int blk = blockIdx.x;
    const int t = threadIdx.x;

    const float *w, *m;
    unsigned* p;
    int unit, src_n, K, DST, lds_off;
    if (blk < 16) {
        w = w_a; m = m_a; p = pa; unit = blk;
        src_n = SRC_A; K = K_A; DST = DST_A; lds_off = 0;
    } else if (blk < 24) {
        w = w_b; m = m_b; p = pb; unit = blk - 16;
        src_n = SRC_B; K = K_B; DST = DST_B; lds_off = 0;
    } else {
        w = w_c; m = m_c; p = pc; unit = blk - 24;
        src_n = SRC_C; K = K_C; DST = DST_C; lds_off = LDS_OFF_C;
    }
    const int dst_base = unit * 64;

    if (t < 64) s_cnt[t] = 0;
    __syncthreads();

    // Phase 1: cooperative row-by-row scan (coalesced float4 mask loads).
    const int nvec = src_n >> 10;  // float4 loads per thread per row: 4 or 2
    for (int r = 0; r < 64; ++r) {
        const float* mrow = m + (size_t)(dst_base + r) * src_n;
        const float* wrow = w + (size_t)(dst_base + r) * src_n;
        const float4* m4 = (const float4*)mrow;
        for (int i = 0; i < nvec; ++i) {
            int q = t + (i << 8);
            float4 mv = m4[q];
#pragma unroll
            for (int j = 0; j < 4; ++j) {
                float mvj = (&mv.x)[j];
                if (mvj != 0.0f) {
                    int e = 4 * q + j;
                    int pos = atomicAdd(&s_cnt[r], 1);
                    if (pos < 64) {
                        unsigned hb = (unsigned)__half_as_ushort(
                            __float2half(wrow[e] * mvj));
                        s_conn[r][pos] = ((unsigned)(lds_off + e) << 16) | hb;
                    }
                }
            }
        }
    }
    __syncthreads();

    // Defensive pad (masks have exactly K nonzeros; never leave poison).
    if (t < 64) {
        int c = s_cnt[t];
        if (c > K) c = K;
        for (int j = c; j < K; ++j)
            s_conn[t][j] = ((unsigned)(lds_off + (j & 31)) << 16);
    }
    __syncthreads();

    // Phase 2: greedy bank matching, wave 0 only (lane = row).
    if (t < 64) {
        const int r = t;
        unsigned long long avail =
            (K == 64) ? ~0ull : ((1ull << K) - 1ull);
        int pos = r & (K - 1);
        for (int k = 0; k < K; ++k) {
            if (t < 32) s_bank[t] = 0;
            __threadfence_block();  // reset visible before this step's atomics
            bool done = false;
            int attempts = 0;
            while (__any(!done)) {
                if (!done) {
                    // next available connection starting at pos
                    unsigned long long mask = avail >> pos;
                    if (mask) pos = pos + (int)__builtin_ctzll(mask);
                    else      pos = (int)__builtin_ctzll(avail);
                    unsigned my = s_conn[r][pos];
                    int bank = (int)((my >> 16) & 31u);
                    int old = atomicAdd(&s_bank[bank], 1);
                    if (old < 2 || attempts >= 6) {
                        done = true;
                        avail &= ~(1ull << pos);
                        p[(size_t)k * DST + dst_base + r] = my;
                        pos = (pos + 1) & (K - 1);
                    } else {
                        atomicSub(&s_bank[bank], 1);
                        pos = (pos + 1) & (K - 1);
                        ++attempts;
                    }
                }
            }
        }
    }
}

// ---------------------------------------------------------------------------
// Kernel 2a: tract a. One block per 4 (b,s) rows. x_a rows staged as two
// fp16x2 regions: region0 = rows{0,1}, region1 = rows{2,3} at +16 KB
// (multiple of 128 B -> same bank for both reads, so one bank schedule
// covers both gathers). Each thread computes 4 dst, each for 4 rows.
// ---------------------------------------------------------------------------
__global__ __launch_bounds__(256) void tract_a_kernel(
    const float* __restrict__ x_a, const unsigned* __restrict__ pa,
    float* __restrict__ out) {
    __shared__ unsigned xs[2][SRC_A];  // 32 KB
    const int t = threadIdx.x;
    const size_t r0 = (size_t)blockIdx.x * 4;
    const float* xr0 = x_a + r0 * SRC_A;
    const float* xr1 = xr0 + SRC_A;
    const float* xr2 = xr1 + SRC_A;
    const float* xr3 = xr2 + SRC_A;

    // Staging: scalar coalesced loads, 2-way (free) LDS store aliasing.
#pragma unroll
    for (int i = 0; i < 16; ++i) {
        int wdx = t + (i << 8);
        __half2 h01 = __floats2half2_rn(xr0[wdx], xr1[wdx]);
        __half2 h23 = __floats2half2_rn(xr2[wdx], xr3[wdx]);
        xs[0][wdx] = *(unsigned*)&h01;
        xs[1][wdx] = *(unsigned*)&h23;
    }
    __syncthreads();

    float* o0 = out + r0 * OUT_DIM;
#pragma unroll
    for (int o = 0; o < 4; ++o) {
        int dst = t + (o << 8);
        float a0 = 0.f, a1 = 0.f, a2 = 0.f, a3 = 0.f;
#pragma unroll 16
        for (int k = 0; k < K_A; ++k) {
            unsigned u = pa[k * DST_A + dst];
            float w = __half2float(__ushort_as_half((unsigned short)(u & 0xffffu)));
            unsigned idx = u >> 16;
            unsigned v01 = xs[0][idx];
            unsigned v23 = xs[1][idx];
            __half2 h01 = *(__half2*)&v01;
            __half2 h23 = *(__half2*)&v23;
            a0 += w * __low2float(h01);
            a1 += w * __high2float(h01);
            a2 += w * __low2float(h23);
            a3 += w * __high2float(h23);
        }
        o0[dst] = a0;
        o0[OUT_DIM + dst] = a1;
        o0[2 * OUT_DIM + dst] = a2;
        o0[3 * OUT_DIM + dst] = a3;
    }
}

// ---------------------------------------------------------------------------
// Kernel 2b: tracts b + c, same structure. LDS word space: b at 0..4095,
// c at 4096..6143; regions 24 KB apart (multiple of 128 B).
// ---------------------------------------------------------------------------
#define BC_WORDS 6144
__global__ __launch_bounds__(256) void tract_bc_kernel(
    const float* __restrict__ x_b, const float* __restrict__ x_c,
    const unsigned* __restrict__ pb, const unsigned* __restrict__ pc,
    float* __restrict__ out) {
    __shared__ unsigned xs[2][BC_WORDS];  // 48 KB
    const int t = threadIdx.x;
    const size_t r0 = (size_t)blockIdx.x * 4;
    const float* b0 = x_b + r0 * SRC_B;
    const float* b1 = b0 + SRC_B;
    const float* b2 = b1 + SRC_B;
    const float* b3 = b2 + SRC_B;
    const float* c0 = x_c + r0 * SRC_C;
    const float* c1 = c0 + SRC_C;
    const float* c2 = c1 + SRC_C;
    const float* c3 = c2 + SRC_C;

#pragma unroll
    for (int i = 0; i < 16; ++i) {
        int wdx = t + (i << 8);
        __half2 h01 = __floats2half2_rn(b0[wdx], b1[wdx]);
        __half2 h23 = __floats2half2_rn(b2[wdx], b3[wdx]);
        xs[0][wdx] = *(unsigned*)&h01;
        xs[1][wdx] = *(unsigned*)&h23;
    }
#pragma unroll
    for (int i = 0; i < 8; ++i) {
        int wdx = t + (i << 8);
        __half2 h01 = __floats2half2_rn(c0[wdx], c1[wdx]);
        __half2 h23 = __floats2half2_rn(c2[wdx], c3[wdx]);
        xs[0][LDS_OFF_C + wdx] = *(unsigned*)&h01;
        xs[1][LDS_OFF_C + wdx] = *(unsigned*)&h23;
    }
    __syncthreads();

    float* o0 = out + r0 * OUT_DIM;

    // tract b: dst = t + o*256, out col 1024 + dst
#pragma unroll
    for (int o = 0; o < 2; ++o) {
        int dst = t + (o << 8);
        float a0 = 0.f, a1 = 0.f, a2 = 0.f, a3 = 0.f;
#pragma unroll 16
        for (int k = 0; k < K_B; ++k) {
            unsigned u = pb[k * DST_B + dst];
            float w = __half2float(__ushort_as_half((unsigned short)(u & 0xffffu)));
            unsigned idx = u >> 16;
            unsigned v01 = xs[0][idx];
            unsigned v23 = xs[1][idx];
            __half2 h01 = *(__half2*)&v01;
            __half2 h23 = *(__half2*)&v23;
            a0 += w * __low2float(h01);
            a1 += w * __high2float(h01);
            a2 += w * __low2float(h23);
            a3 += w * __high2float(h23);
        }
        int col = DST_A + dst;
        o0[col] = a0;
        o0[OUT_DIM + col] = a1;
        o0[2 * OUT_DIM + col] = a2;
        o0[3 * OUT_DIM + col] = a3;
    }
    // tract c: idx already offset by LDS_OFF_C in the table
#pragma unroll
    for (int o = 0; o < 2; ++o) {
        int dst = t + (o << 8);
        float a0 = 0.f, a1 = 0.f, a2 = 0.f, a3 = 0.f;
#pragma unroll 16
        for (int k = 0; k < K_C; ++k) {
            unsigned u = pc[k * DST_C + dst];
            float w = __half2float(__ushort_as_half((unsigned short)(u & 0xffffu)));
            unsigned idx = u >> 16;
            unsigned v01 = xs[0][idx];
            unsigned v23 = xs[1][idx];
            __half2 h01 = *(__half2*)&v01;
            __half2 h23 = *(__half2*)&v23;
            a0 += w * __low2float(h01);
            a1 += w * __high2float(h01);
            a2 += w * __low2float(h23);
            a3 += w * __high2float(h23);
        }
        int col = DST_A + DST_B + dst;
        o0[col] = a0;
        o0[OUT_DIM + col] = a1;
        o0[2 * OUT_DIM + col] = a2;
        o0[3 * OUT_DIM + col] = a3;
    }
}

// ---------------------------------------------------------------------------
extern "C" void kernel_launch(void* const* d_in, const int* in_sizes, int n_in,
                              void* d_out, int out_size, void* d_ws, size_t ws_size,
                              hipStream_t stream) {
    // setup_inputs() dict order: x_a, w_a, m_a, x_b, w_b, m_b, x_c, w_c, m_c
    const float* x_a = (const float*)d_in[0];
    const float* w_a = (const float*)d_in[1];
    const float* m_a = (const float*)d_in[2];
    const float* x_b = (const float*)d_in[3];
    const float* w_b = (const float*)d_in[4];
    const float* m_b = (const float*)d_in[5];
    const float* x_c = (const float*)d_in[6];
    const float* w_c = (const float*)d_in[7];
    const float* m_c = (const float*)d_in[8];
    float* out = (float*)d_out;

    // Workspace: packed pair tables (uint32 = idx<<16 | fp16 w).
    //   pa: 64*1024*4 = 262144 B, pb: 64*512*4 = 131072 B, pc: 32*512*4 = 65536 B
    char* ws = (char*)d_ws;
    unsigned* pa = (unsigned*)(ws);
    unsigned* pb = (unsigned*)(ws + 262144);
    unsigned* pc = (unsigned*)(ws + 262144 + 131072);

    // 32 units of 64 dst rows: a=16, b=8, c=8.
    compress_kernel<<<32, 256, 0, stream>>>(w_a, m_a, w_b, m_b, w_c, m_c,
                                            pa, pb, pc);
    tract_a_kernel<<<BS_TOTAL / 4, 256, 0, stream>>>(x_a, pa, out);
    tract_bc_kernel<<<BS_TOTAL / 4, 256, 0, stream>>>(x_b, x_c, pb, pc, out);
}